// Round 3
// baseline (186.796 us; speedup 1.0000x reference)
//
#include <hip/hip_runtime.h>
#include <hip/hip_bf16.h>
#include <hip/hip_fp16.h>
#include <type_traits>

// f32 in / f32 out. Round-6: M_TILE 32->64. Rationale: VGPR total (60 arch +
// 16 AGPR ~ 76) already lands in the 65-128 bucket -> 4 waves/SIMD regardless,
// so ~50 regs/wave are free. Spend them on a 64-edge tile: half the barrier
// convergences per edge, 2x outstanding gather loads (latency MLP), 2x MFMA +
// epilogue work per barrier. GRID back to 512 (2 blocks/CU resident = the
// register-bucket limit). Tail tile (500000 = 64*7812+32) via clamp + guard.
// Keeps: fp16 z pre-pass (half gather bytes), packed v_pk_mul_f16, f16 MFMA,
// software-pipelined gather (edge idx 2 tiles ahead, z rows 1 tile ahead),
// double-buffered LDS, ONE barrier per tile.

#define N_NODES 100000
#define N_EDGES 500000
#define D_IN    128
#define D_HID   256
#define M_TILE  64
#define NTILES  ((N_EDGES + M_TILE - 1) / M_TILE)   // 7813 (last tile: 32 valid)
#define LDS_STRIDE 136               // 128 + 8 elements pad (2B elements)
#define GRID    512                  // 2 blocks/CU resident (reg-bucket limit)

typedef _Float16 half8  __attribute__((ext_vector_type(8)));
typedef __bf16   bf16x8 __attribute__((ext_vector_type(8)));
typedef float    f32x4  __attribute__((ext_vector_type(4)));
typedef float    f32x2  __attribute__((ext_vector_type(2)));

union F4H { float4 v; f32x2 h[2]; };

__device__ __forceinline__ unsigned int pkbf(f32x2 q) {
    union { __hip_bfloat162 b; unsigned int u; } c;
    c.b = __float22bfloat162_rn(make_float2(q.x, q.y));   // RNE packed cvt
    return c.u;
}

// mish(x) = x * N/(N+2), N = E*(E+2), E = e^x — float2-vectorized
__device__ __forceinline__ f32x2 mish2(f32x2 x) {
    f32x2 xc = {fminf(x.x, 20.0f), fminf(x.y, 20.0f)};
    f32x2 E  = {__expf(xc.x), __expf(xc.y)};
    f32x2 num = E * (E + 2.0f);
    f32x2 den = num + 2.0f;
    f32x2 r  = {__builtin_amdgcn_rcpf(den.x), __builtin_amdgcn_rcpf(den.y)};
    return x * num * r;
}

// ---- pre-pass: z f32 -> fp16 (RNE), fully coalesced, BW-bound ----
__global__ __launch_bounds__(256)
void zcvt_kernel(const float* __restrict__ z, _Float16* __restrict__ zh) {
    const size_t i = (size_t)blockIdx.x * 256 + threadIdx.x;   // chunk id
    const float4 f0 = *reinterpret_cast<const float4*>(z + i * 8);
    const float4 f1 = *reinterpret_cast<const float4*>(z + i * 8 + 4);
    union { half8 h; uint4 u; } o;
    o.h[0] = (_Float16)f0.x; o.h[1] = (_Float16)f0.y;
    o.h[2] = (_Float16)f0.z; o.h[3] = (_Float16)f0.w;
    o.h[4] = (_Float16)f1.x; o.h[5] = (_Float16)f1.y;
    o.h[6] = (_Float16)f1.z; o.h[7] = (_Float16)f1.w;
    *reinterpret_cast<uint4*>(zh + i * 8) = o.u;
}

template <bool USE_H>
__global__ __launch_bounds__(512, 4)
void edge_decoder_kernel(const float*    __restrict__ z,
                         const _Float16* __restrict__ zh,
                         const int*      __restrict__ edge,
                         const float*    __restrict__ W1,
                         const float*    __restrict__ b1,
                         const float*    __restrict__ W2,
                         const float*    __restrict__ b2,
                         float*          __restrict__ out) {
    using frag_t = std::conditional_t<USE_H, half8, bf16x8>;

    __shared__ ushort xbuf[2][M_TILE * LDS_STRIDE];   // 2 x 17.4 KB
    __shared__ float  lpart[2][8][M_TILE];            // 4 KB

    const int t    = threadIdx.x;
    const int wave = t >> 6;          // 0..7
    const int lane = t & 63;
    const int quad = lane >> 4;
    const int nlo  = lane & 15;

    // ---- W1 -> B-fragments (wave owns hidden cols [32w, 32w+32)) ----
    frag_t bfrag[4][2];               // [ks][nt] = 32 VGPRs
    float  b1f[2], w2f[2];
    #pragma unroll
    for (int nt = 0; nt < 2; ++nt) {
        const int n = wave * 32 + nt * 16 + nlo;
        const float* wrow = W1 + n * D_IN;
        #pragma unroll
        for (int ks = 0; ks < 4; ++ks) {
            float4 w0 = *reinterpret_cast<const float4*>(wrow + ks * 32 + quad * 8);
            float4 w1 = *reinterpret_cast<const float4*>(wrow + ks * 32 + quad * 8 + 4);
            float wa[8] = {w0.x, w0.y, w0.z, w0.w, w1.x, w1.y, w1.z, w1.w};
            if constexpr (USE_H) {
                half8 hv;
                #pragma unroll
                for (int j = 0; j < 8; ++j) hv[j] = (_Float16)wa[j];
                bfrag[ks][nt] = hv;
            } else {
                bf16x8 bv;
                #pragma unroll
                for (int j = 0; j < 8; ++j) bv[j] = (__bf16)wa[j];
                bfrag[ks][nt] = bv;
            }
        }
        b1f[nt] = b1[n];
        w2f[nt] = W2[n];
    }
    const float b2f = b2[0];

    // ---- gather assignment: thread covers slots s_slot and s_slot+32 ----
    const int s_slot = t >> 4;        // 0..31
    const int cch    = t & 15;        // 0..15

    // ---- pipeline prologue ----
    int tile = blockIdx.x;
    float4 a0[2], a1[2], c0[2], c1[2];   // f32 path gather regs (2 slots)
    half8  ha[2], hc[2];                 // fp16 path gather regs (2 slots)
    {
        const int e0 = tile * M_TILE + s_slot;       // always < N_EDGES
        const int e1 = e0 + 32;                      // tile<GRID so valid
        const int u0 = edge[e0], v0 = edge[N_EDGES + e0];
        const int u1 = edge[e1], v1 = edge[N_EDGES + e1];
        if constexpr (USE_H) {
            ha[0] = *reinterpret_cast<const half8*>(zh + (size_t)u0 * D_IN + cch * 8);
            hc[0] = *reinterpret_cast<const half8*>(zh + (size_t)v0 * D_IN + cch * 8);
            ha[1] = *reinterpret_cast<const half8*>(zh + (size_t)u1 * D_IN + cch * 8);
            hc[1] = *reinterpret_cast<const half8*>(zh + (size_t)v1 * D_IN + cch * 8);
        } else {
            const float* zu0 = z + (size_t)u0 * D_IN + cch * 8;
            const float* zv0 = z + (size_t)v0 * D_IN + cch * 8;
            const float* zu1 = z + (size_t)u1 * D_IN + cch * 8;
            const float* zv1 = z + (size_t)v1 * D_IN + cch * 8;
            a0[0] = *reinterpret_cast<const float4*>(zu0);
            a1[0] = *reinterpret_cast<const float4*>(zu0 + 4);
            c0[0] = *reinterpret_cast<const float4*>(zv0);
            c1[0] = *reinterpret_cast<const float4*>(zv0 + 4);
            a0[1] = *reinterpret_cast<const float4*>(zu1);
            a1[1] = *reinterpret_cast<const float4*>(zu1 + 4);
            c0[1] = *reinterpret_cast<const float4*>(zv1);
            c1[1] = *reinterpret_cast<const float4*>(zv1 + 4);
        }
    }
    // edge indices for tile+GRID
    int u_n[2], v_n[2];
    {
        const int t1 = min(tile + GRID, NTILES - 1);
        const int e0 = t1 * M_TILE + s_slot;                 // slot<32: always valid
        const int e1 = min(e0 + 32, N_EDGES - 1);            // clamp tail
        u_n[0] = edge[e0]; v_n[0] = edge[N_EDGES + e0];
        u_n[1] = edge[e1]; v_n[1] = edge[N_EDGES + e1];
    }

    int  p = 0;
    bool have_prev = false;
    int  prev_base = 0;

    for (; tile < NTILES; tile += GRID) {
        // ---- A: current tile's gathered pair-product -> xbuf[p] (2 slots) ----
        if constexpr (USE_H) {
            union { half8 h; uint4 u; } pr0, pr1;
            pr0.h = ha[0] * hc[0];                // 4x v_pk_mul_f16
            pr1.h = ha[1] * hc[1];
            *reinterpret_cast<uint4*>(&xbuf[p][s_slot * LDS_STRIDE + cch * 8]) = pr0.u;
            *reinterpret_cast<uint4*>(&xbuf[p][(s_slot + 32) * LDS_STRIDE + cch * 8]) = pr1.u;
        } else {
            #pragma unroll
            for (int s = 0; s < 2; ++s) {
                F4H A0{a0[s]}, A1{a1[s]}, C0{c0[s]}, C1{c1[s]};
                unsigned int r0 = pkbf(A0.h[0] * C0.h[0]);
                unsigned int r1 = pkbf(A0.h[1] * C0.h[1]);
                unsigned int r2 = pkbf(A1.h[0] * C1.h[0]);
                unsigned int r3 = pkbf(A1.h[1] * C1.h[1]);
                *reinterpret_cast<uint4*>(&xbuf[p][(s_slot + 32 * s) * LDS_STRIDE + cch * 8]) =
                    make_uint4(r0, r1, r2, r3);
            }
        }
        // ---- B: the single barrier ----
        __syncthreads();

        // ---- C: issue next tile's z loads (indices already resident) +
        //          edge-index loads 2 tiles ahead ----
        if constexpr (USE_H) {
            ha[0] = *reinterpret_cast<const half8*>(zh + (size_t)u_n[0] * D_IN + cch * 8);
            hc[0] = *reinterpret_cast<const half8*>(zh + (size_t)v_n[0] * D_IN + cch * 8);
            ha[1] = *reinterpret_cast<const half8*>(zh + (size_t)u_n[1] * D_IN + cch * 8);
            hc[1] = *reinterpret_cast<const half8*>(zh + (size_t)v_n[1] * D_IN + cch * 8);
        } else {
            const float* zu0 = z + (size_t)u_n[0] * D_IN + cch * 8;
            const float* zv0 = z + (size_t)v_n[0] * D_IN + cch * 8;
            const float* zu1 = z + (size_t)u_n[1] * D_IN + cch * 8;
            const float* zv1 = z + (size_t)v_n[1] * D_IN + cch * 8;
            a0[0] = *reinterpret_cast<const float4*>(zu0);
            a1[0] = *reinterpret_cast<const float4*>(zu0 + 4);
            c0[0] = *reinterpret_cast<const float4*>(zv0);
            c1[0] = *reinterpret_cast<const float4*>(zv0 + 4);
            a0[1] = *reinterpret_cast<const float4*>(zu1);
            a1[1] = *reinterpret_cast<const float4*>(zu1 + 4);
            c0[1] = *reinterpret_cast<const float4*>(zv1);
            c1[1] = *reinterpret_cast<const float4*>(zv1 + 4);
        }
        {
            const int t2 = min(tile + 2 * GRID, NTILES - 1);
            const int e0 = t2 * M_TILE + s_slot;
            const int e1 = min(e0 + 32, N_EDGES - 1);
            u_n[0] = edge[e0]; v_n[0] = edge[N_EDGES + e0];
            u_n[1] = edge[e1]; v_n[1] = edge[N_EDGES + e1];
        }

        // ---- E: combine + store PREVIOUS tile (lpart[p^1] sealed by barrier) ----
        if (have_prev) {
            if (t < M_TILE) {
                const int eo = prev_base + t;
                if (eo < N_EDGES) {
                    const int pp = p ^ 1;
                    float logit = b2f;
                    #pragma unroll
                    for (int w = 0; w < 8; ++w) logit += lpart[pp][w][t];
                    out[eo] = __builtin_amdgcn_rcpf(1.0f + __expf(-logit));
                }
            }
        }

        // ---- D: MFMA + epilogue for current tile -> lpart[p] ----
        f32x4 acc[4][2];
        #pragma unroll
        for (int mt = 0; mt < 4; ++mt)
            #pragma unroll
            for (int nt = 0; nt < 2; ++nt)
                acc[mt][nt] = (f32x4){0.f, 0.f, 0.f, 0.f};

        #pragma unroll
        for (int ks = 0; ks < 4; ++ks) {
            frag_t af[4];
            #pragma unroll
            for (int mt = 0; mt < 4; ++mt)
                af[mt] = *reinterpret_cast<const frag_t*>(
                    &xbuf[p][(mt * 16 + nlo) * LDS_STRIDE + ks * 32 + quad * 8]);
            #pragma unroll
            for (int mt = 0; mt < 4; ++mt)
                #pragma unroll
                for (int nt = 0; nt < 2; ++nt) {
                    if constexpr (USE_H)
                        acc[mt][nt] = __builtin_amdgcn_mfma_f32_16x16x32_f16(
                            af[mt], bfrag[ks][nt], acc[mt][nt], 0, 0, 0);
                    else
                        acc[mt][nt] = __builtin_amdgcn_mfma_f32_16x16x32_bf16(
                            af[mt], bfrag[ks][nt], acc[mt][nt], 0, 0, 0);
                }
        }

        // D layout: row = mt*16 + quad*4 + r, col = nlo + 16nt (+32*wave)
        #pragma unroll
        for (int mt = 0; mt < 4; ++mt) {
            #pragma unroll
            for (int pr = 0; pr < 2; ++pr) {
                f32x2 s2 = {0.f, 0.f};
                #pragma unroll
                for (int nt = 0; nt < 2; ++nt) {
                    f32x2 h = {acc[mt][nt][2 * pr]     + b1f[nt],
                               acc[mt][nt][2 * pr + 1] + b1f[nt]};
                    f32x2 m = mish2(h);
                    s2.x += m.x * w2f[nt];
                    s2.y += m.y * w2f[nt];
                }
                float sx = s2.x, sy = s2.y;
                sx += __shfl_xor(sx, 1); sy += __shfl_xor(sy, 1);
                sx += __shfl_xor(sx, 2); sy += __shfl_xor(sy, 2);
                sx += __shfl_xor(sx, 4); sy += __shfl_xor(sy, 4);
                sx += __shfl_xor(sx, 8); sy += __shfl_xor(sy, 8);
                if (nlo == 0) {
                    const int row = mt * 16 + quad * 4 + pr * 2;
                    lpart[p][wave][row]     = sx;
                    lpart[p][wave][row + 1] = sy;
                }
            }
        }

        have_prev = true;
        prev_base = tile * M_TILE;
        p ^= 1;
    }

    // ---- drain: last tile's logits ----
    __syncthreads();
    if (have_prev && t < M_TILE) {
        const int eo = prev_base + t;
        if (eo < N_EDGES) {
            const int pp = p ^ 1;
            float logit = b2f;
            #pragma unroll
            for (int w = 0; w < 8; ++w) logit += lpart[pp][w][t];
            out[eo] = __builtin_amdgcn_rcpf(1.0f + __expf(-logit));
        }
    }
}

extern "C" void kernel_launch(void* const* d_in, const int* in_sizes, int n_in,
                              void* d_out, int out_size, void* d_ws, size_t ws_size,
                              hipStream_t stream) {
    const float* z    = (const float*)d_in[0];
    const int*   edge = (const int*)d_in[1];
    const float* W1   = (const float*)d_in[2];
    const float* b1   = (const float*)d_in[3];
    const float* W2   = (const float*)d_in[4];
    const float* b2   = (const float*)d_in[5];
    float* out = (float*)d_out;

    const size_t zh_bytes = (size_t)N_NODES * D_IN * sizeof(_Float16);  // 25.6 MB
    if (d_ws != nullptr && ws_size >= zh_bytes) {
        _Float16* zh = (_Float16*)d_ws;
        zcvt_kernel<<<dim3(N_NODES * D_IN / 8 / 256), dim3(256), 0, stream>>>(z, zh);
        edge_decoder_kernel<true><<<dim3(GRID), dim3(512), 0, stream>>>(
            z, zh, edge, W1, b1, W2, b2, out);
    } else {
        edge_decoder_kernel<false><<<dim3(GRID), dim3(512), 0, stream>>>(
            z, nullptr, edge, W1, b1, W2, b2, out);
    }
}

// Round 4
// 165.880 us; speedup vs baseline: 1.1261x; 1.1261x over previous
//
#include <hip/hip_runtime.h>
#include <hip/hip_bf16.h>
#include <hip/hip_fp16.h>
#include <type_traits>

// f32 in / f32 out. Round-7: SWAPPED MFMA. mfma(W1frag, xfrag) instead of
// mfma(xfrag, W1frag): D is now [hidden x edge], so each lane holds 8 hidden
// values of ONE edge -> fc2 dot is lane-local (8 packed fmas) and the
// cross-lane reduce is 2 shuffles (xor16, xor32) instead of 32. Cuts ~80
// issued instrs/thread/tile + four 100-cyc-deep swizzle chains. M_TILE back
// to 32 (r3's 64 was neutral, cost regs). Gather byte-offsets precomputed at
// edge-prefetch time (2 tiles ahead). Keeps: fp16 z pre-pass, v_pk_mul_f16
// pair product, double-buffered LDS, ONE barrier per tile, GRID=1024.

#define N_NODES 100000
#define N_EDGES 500000
#define D_IN    128
#define D_HID   256
#define M_TILE  32
#define NTILES  (N_EDGES / M_TILE)   // 15625 exactly, no partial tile
#define LDS_STRIDE 136               // 128 + 8 elements pad (2B elements)
#define GRID    1024

typedef _Float16 half8  __attribute__((ext_vector_type(8)));
typedef __bf16   bf16x8 __attribute__((ext_vector_type(8)));
typedef float    f32x4  __attribute__((ext_vector_type(4)));
typedef float    f32x2  __attribute__((ext_vector_type(2)));

union F4H { float4 v; f32x2 h[2]; };

__device__ __forceinline__ unsigned int pkbf(f32x2 q) {
    union { __hip_bfloat162 b; unsigned int u; } c;
    c.b = __float22bfloat162_rn(make_float2(q.x, q.y));   // RNE packed cvt
    return c.u;
}

// mish(x) = x * N/(N+2), N = E*(E+2), E = e^x — float2-vectorized
__device__ __forceinline__ f32x2 mish2(f32x2 x) {
    f32x2 xc = {fminf(x.x, 20.0f), fminf(x.y, 20.0f)};
    f32x2 E  = {__expf(xc.x), __expf(xc.y)};
    f32x2 num = E * (E + 2.0f);
    f32x2 den = num + 2.0f;
    f32x2 r  = {__builtin_amdgcn_rcpf(den.x), __builtin_amdgcn_rcpf(den.y)};
    return x * num * r;
}

// ---- pre-pass: z f32 -> fp16 (RNE), fully coalesced, BW-bound ----
__global__ __launch_bounds__(256)
void zcvt_kernel(const float* __restrict__ z, _Float16* __restrict__ zh) {
    const size_t i = (size_t)blockIdx.x * 256 + threadIdx.x;   // chunk id
    const float4 f0 = *reinterpret_cast<const float4*>(z + i * 8);
    const float4 f1 = *reinterpret_cast<const float4*>(z + i * 8 + 4);
    union { half8 h; uint4 u; } o;
    o.h[0] = (_Float16)f0.x; o.h[1] = (_Float16)f0.y;
    o.h[2] = (_Float16)f0.z; o.h[3] = (_Float16)f0.w;
    o.h[4] = (_Float16)f1.x; o.h[5] = (_Float16)f1.y;
    o.h[6] = (_Float16)f1.z; o.h[7] = (_Float16)f1.w;
    *reinterpret_cast<uint4*>(zh + i * 8) = o.u;
}

template <bool USE_H>
__global__ __launch_bounds__(512, 4)
void edge_decoder_kernel(const float*    __restrict__ z,
                         const _Float16* __restrict__ zh,
                         const int*      __restrict__ edge,
                         const float*    __restrict__ W1,
                         const float*    __restrict__ b1,
                         const float*    __restrict__ W2,
                         const float*    __restrict__ b2,
                         float*          __restrict__ out) {
    using frag_t = std::conditional_t<USE_H, half8, bf16x8>;

    __shared__ ushort xbuf[2][M_TILE * LDS_STRIDE];   // 2 x 8.7 KB
    __shared__ float  lpart[2][8][M_TILE];            // 2 KB

    const int t    = threadIdx.x;
    const int wave = t >> 6;          // 0..7
    const int lane = t & 63;
    const int quad = lane >> 4;
    const int nlo  = lane & 15;

    // ---- W1 -> fragments (wave owns hidden cols [32w, 32w+32)) ----
    // Used as the A-operand of the swapped mfma: lane l&15 = W1 row (hidden).
    frag_t bfrag[4][2];               // [ks][nt] = 32 VGPRs
    #pragma unroll
    for (int nt = 0; nt < 2; ++nt) {
        const int n = wave * 32 + nt * 16 + nlo;
        const float* wrow = W1 + n * D_IN;
        #pragma unroll
        for (int ks = 0; ks < 4; ++ks) {
            float4 w0 = *reinterpret_cast<const float4*>(wrow + ks * 32 + quad * 8);
            float4 w1 = *reinterpret_cast<const float4*>(wrow + ks * 32 + quad * 8 + 4);
            float wa[8] = {w0.x, w0.y, w0.z, w0.w, w1.x, w1.y, w1.z, w1.w};
            if constexpr (USE_H) {
                half8 hv;
                #pragma unroll
                for (int j = 0; j < 8; ++j) hv[j] = (_Float16)wa[j];
                bfrag[ks][nt] = hv;
            } else {
                bf16x8 bv;
                #pragma unroll
                for (int j = 0; j < 8; ++j) bv[j] = (__bf16)wa[j];
                bfrag[ks][nt] = bv;
            }
        }
    }
    // Swapped-D layout: lane holds hidden rows {nt*16 + quad*4 + r}, edge col nlo.
    // Preload b1/w2 for this lane's 8 hidden rows as f32x2 pairs.
    f32x2 b1p[2][2], w2p[2][2];       // [nt][pair]
    #pragma unroll
    for (int nt = 0; nt < 2; ++nt) {
        const int nb = wave * 32 + nt * 16 + quad * 4;
        b1p[nt][0] = (f32x2){b1[nb],     b1[nb + 1]};
        b1p[nt][1] = (f32x2){b1[nb + 2], b1[nb + 3]};
        w2p[nt][0] = (f32x2){W2[nb],     W2[nb + 1]};
        w2p[nt][1] = (f32x2){W2[nb + 2], W2[nb + 3]};
    }
    const float b2f = b2[0];

    // ---- gather assignment: slot = edge within tile, cch = 8-elem chunk ----
    const int s_slot = t >> 4;        // 0..31
    const int cch    = t & 15;        // 0..15

    // ---- pipeline prologue ----
    int tile = blockIdx.x;
    float4 a0, a1, c0, c1;            // f32 path gather regs
    half8  ha, hc;                    // fp16 path gather regs
    {
        const int e = tile * M_TILE + s_slot;
        const int u = edge[e], v = edge[N_EDGES + e];
        if constexpr (USE_H) {
            ha = *reinterpret_cast<const half8*>(zh + (size_t)u * D_IN + cch * 8);
            hc = *reinterpret_cast<const half8*>(zh + (size_t)v * D_IN + cch * 8);
        } else {
            const float* zu = z + (size_t)u * D_IN + cch * 8;
            const float* zv = z + (size_t)v * D_IN + cch * 8;
            a0 = *reinterpret_cast<const float4*>(zu);
            a1 = *reinterpret_cast<const float4*>(zu + 4);
            c0 = *reinterpret_cast<const float4*>(zv);
            c1 = *reinterpret_cast<const float4*>(zv + 4);
        }
    }
    // next tile's gather addresses: USE_H stores precomputed BYTE offsets
    // (u*256 + cch*16, fits int), f32 path stores raw node indices.
    int u_n, v_n;
    {
        const int t1 = min(tile + GRID, NTILES - 1);
        const int e1 = t1 * M_TILE + s_slot;
        if constexpr (USE_H) {
            u_n = edge[e1] * 256 + cch * 16;
            v_n = edge[N_EDGES + e1] * 256 + cch * 16;
        } else {
            u_n = edge[e1]; v_n = edge[N_EDGES + e1];
        }
    }

    int  p = 0;
    bool have_prev = false;
    int  prev_base = 0;

    for (; tile < NTILES; tile += GRID) {
        // ---- A: current tile's gathered pair-product -> xbuf[p] ----
        if constexpr (USE_H) {
            union { half8 h; uint4 u; } pr;
            pr.h = ha * hc;                       // 4x v_pk_mul_f16
            *reinterpret_cast<uint4*>(&xbuf[p][s_slot * LDS_STRIDE + cch * 8]) = pr.u;
        } else {
            F4H A0{a0}, A1{a1}, C0{c0}, C1{c1};
            unsigned int r0 = pkbf(A0.h[0] * C0.h[0]);
            unsigned int r1 = pkbf(A0.h[1] * C0.h[1]);
            unsigned int r2 = pkbf(A1.h[0] * C1.h[0]);
            unsigned int r3 = pkbf(A1.h[1] * C1.h[1]);
            *reinterpret_cast<uint4*>(&xbuf[p][s_slot * LDS_STRIDE + cch * 8]) =
                make_uint4(r0, r1, r2, r3);
        }
        // ---- B: the single barrier ----
        __syncthreads();

        // ---- C: issue next tile's z loads (addresses already resident) +
        //          edge-index loads 2 tiles ahead ----
        if constexpr (USE_H) {
            ha = *reinterpret_cast<const half8*>(
                     reinterpret_cast<const char*>(zh) + u_n);
            hc = *reinterpret_cast<const half8*>(
                     reinterpret_cast<const char*>(zh) + v_n);
        } else {
            const float* zu = z + (size_t)u_n * D_IN + cch * 8;
            const float* zv = z + (size_t)v_n * D_IN + cch * 8;
            a0 = *reinterpret_cast<const float4*>(zu);
            a1 = *reinterpret_cast<const float4*>(zu + 4);
            c0 = *reinterpret_cast<const float4*>(zv);
            c1 = *reinterpret_cast<const float4*>(zv + 4);
        }
        {
            const int t2 = min(tile + 2 * GRID, NTILES - 1);
            const int e2 = t2 * M_TILE + s_slot;
            if constexpr (USE_H) {
                u_n = edge[e2] * 256 + cch * 16;
                v_n = edge[N_EDGES + e2] * 256 + cch * 16;
            } else {
                u_n = edge[e2]; v_n = edge[N_EDGES + e2];
            }
        }

        // ---- E: combine + store PREVIOUS tile (lpart[p^1] sealed by barrier) ----
        if (have_prev) {
            if (t < M_TILE) {
                const int pp = p ^ 1;
                float logit = b2f;
                #pragma unroll
                for (int w = 0; w < 8; ++w) logit += lpart[pp][w][t];
                out[prev_base + t] = __builtin_amdgcn_rcpf(1.0f + __expf(-logit));
            }
        }

        // ---- D: swapped MFMA + epilogue for current tile -> lpart[p] ----
        f32x4 acc[2][2];   // [mt][nt]; D row = hidden (quad*4+r), col = edge (nlo)
        #pragma unroll
        for (int mt = 0; mt < 2; ++mt)
            #pragma unroll
            for (int nt = 0; nt < 2; ++nt)
                acc[mt][nt] = (f32x4){0.f, 0.f, 0.f, 0.f};

        #pragma unroll
        for (int ks = 0; ks < 4; ++ks) {
            frag_t af[2];   // x-fragment: lane l&15 = edge row mt*16+nlo
            #pragma unroll
            for (int mt = 0; mt < 2; ++mt)
                af[mt] = *reinterpret_cast<const frag_t*>(
                    &xbuf[p][(mt * 16 + nlo) * LDS_STRIDE + ks * 32 + quad * 8]);
            #pragma unroll
            for (int mt = 0; mt < 2; ++mt)
                #pragma unroll
                for (int nt = 0; nt < 2; ++nt) {
                    if constexpr (USE_H)
                        acc[mt][nt] = __builtin_amdgcn_mfma_f32_16x16x32_f16(
                            bfrag[ks][nt], af[mt], acc[mt][nt], 0, 0, 0);
                    else
                        acc[mt][nt] = __builtin_amdgcn_mfma_f32_16x16x32_bf16(
                            bfrag[ks][nt], af[mt], acc[mt][nt], 0, 0, 0);
                }
        }

        // Epilogue: lane-local mish + fc2 dot over this lane's 8 hidden rows,
        // then 2-step cross-quad reduce (xor16, xor32). Edge = mt*16 + nlo.
        #pragma unroll
        for (int mt = 0; mt < 2; ++mt) {
            f32x2 dot = {0.f, 0.f};
            #pragma unroll
            for (int nt = 0; nt < 2; ++nt) {
                f32x2 h0 = (f32x2){acc[mt][nt][0], acc[mt][nt][1]} + b1p[nt][0];
                f32x2 h1 = (f32x2){acc[mt][nt][2], acc[mt][nt][3]} + b1p[nt][1];
                f32x2 m0 = mish2(h0);
                f32x2 m1 = mish2(h1);
                dot += m0 * w2p[nt][0];
                dot += m1 * w2p[nt][1];
            }
            float s = dot.x + dot.y;
            s += __shfl_xor(s, 16);
            s += __shfl_xor(s, 32);
            if (quad == 0) lpart[p][wave][mt * 16 + nlo] = s;
        }

        have_prev = true;
        prev_base = tile * M_TILE;
        p ^= 1;
    }

    // ---- drain: last tile's logits ----
    __syncthreads();
    if (have_prev && t < M_TILE) {
        const int pp = p ^ 1;
        float logit = b2f;
        #pragma unroll
        for (int w = 0; w < 8; ++w) logit += lpart[pp][w][t];
        out[prev_base + t] = __builtin_amdgcn_rcpf(1.0f + __expf(-logit));
    }
}

extern "C" void kernel_launch(void* const* d_in, const int* in_sizes, int n_in,
                              void* d_out, int out_size, void* d_ws, size_t ws_size,
                              hipStream_t stream) {
    const float* z    = (const float*)d_in[0];
    const int*   edge = (const int*)d_in[1];
    const float* W1   = (const float*)d_in[2];
    const float* b1   = (const float*)d_in[3];
    const float* W2   = (const float*)d_in[4];
    const float* b2   = (const float*)d_in[5];
    float* out = (float*)d_out;

    const size_t zh_bytes = (size_t)N_NODES * D_IN * sizeof(_Float16);  // 25.6 MB
    if (d_ws != nullptr && ws_size >= zh_bytes) {
        _Float16* zh = (_Float16*)d_ws;
        zcvt_kernel<<<dim3(N_NODES * D_IN / 8 / 256), dim3(256), 0, stream>>>(z, zh);
        edge_decoder_kernel<true><<<dim3(GRID), dim3(512), 0, stream>>>(
            z, zh, edge, W1, b1, W2, b2, out);
    } else {
        edge_decoder_kernel<false><<<dim3(GRID), dim3(512), 0, stream>>>(
            z, nullptr, edge, W1, b1, W2, b2, out);
    }
}

// Round 7
// 165.549 us; speedup vs baseline: 1.1283x; 1.0020x over previous
//
#include <hip/hip_runtime.h>
#include <hip/hip_bf16.h>
#include <hip/hip_fp16.h>
#include <type_traits>

// f32 in / f32 out. Round-10: PACKED-F16 EPILOGUE, take 3. Round-9 failed:
// __builtin_amdgcn_cvt_pkrtz returns __fp16-vec2, not _Float16-vec2 -> one
// __builtin_bit_cast fixes it. Otherwise identical to round-9: native
// _Float16 ext-vector ops (-> v_pk_*_f16), inline-asm v_exp_f16 / v_rcp_f16,
// mish in packed f16 with x<=5 clamp (E*(E+2) < f16-max, factor err <=7e-4).
// Cuts ~60 VALU/tile-wave vs the 87 us round-7 kernel. Next-tile z loads +
// edge-idx loads issued BEFORE the barrier. Keeps: swapped MFMA (r7), fp16 z
// pre-pass, double-buffered LDS, ONE barrier per tile, M_TILE=32, GRID=1024.

#define N_NODES 100000
#define N_EDGES 500000
#define D_IN    128
#define D_HID   256
#define M_TILE  32
#define NTILES  (N_EDGES / M_TILE)   // 15625 exactly, no partial tile
#define LDS_STRIDE 136               // 128 + 8 elements pad (2B elements)
#define GRID    1024

typedef _Float16 half8  __attribute__((ext_vector_type(8)));
typedef _Float16 h2     __attribute__((ext_vector_type(2)));
typedef __fp16   fp16x2 __attribute__((ext_vector_type(2)));
typedef __bf16   bf16x8 __attribute__((ext_vector_type(8)));
typedef float    f32x4  __attribute__((ext_vector_type(4)));
typedef float    f32x2  __attribute__((ext_vector_type(2)));

union F4H { float4 v; f32x2 h[2]; };

__device__ __forceinline__ unsigned int pkbf(f32x2 q) {
    union { __hip_bfloat162 b; unsigned int u; } c;
    c.b = __float22bfloat162_rn(make_float2(q.x, q.y));   // RNE packed cvt
    return c.u;
}

// one-instr packed f32->f16 (RTZ) straight from two acc registers
__device__ __forceinline__ h2 pkh(float a, float b) {
    fp16x2 r = __builtin_amdgcn_cvt_pkrtz(a, b);
    return __builtin_bit_cast(h2, r);
}

__device__ __forceinline__ _Float16 exp2h(_Float16 x) {   // 2^x
    _Float16 r; asm("v_exp_f16 %0, %1" : "=v"(r) : "v"(x)); return r;
}
__device__ __forceinline__ _Float16 rcph(_Float16 x) {    // 1/x
    _Float16 r; asm("v_rcp_f16 %0, %1" : "=v"(r) : "v"(x)); return r;
}

// mish(x) = x * N/(N+2), N = E*(E+2), E = e^min(x,5) — packed f16.
// Clamp 5.0: N <= 148.4*150.4 = 22.3K < 65504 (f16 max). For x>5 the true
// factor is 1-9e-5 ~ 1, error <= 7e-4 abs. x<<0: E underflows -> m -> 0.
__device__ __forceinline__ h2 mish_h2(h2 x) {
    const _Float16 k5 = (_Float16)5.0f;
    h2 xc;
    xc.x = x.x < k5 ? x.x : k5;            // v_min_f16
    xc.y = x.y < k5 ? x.y : k5;
    h2 xs = xc * (_Float16)1.44269504f;    // v_pk_mul (log2 e)
    h2 E;
    E.x = exp2h(xs.x); E.y = exp2h(xs.y);  // 2x v_exp_f16
    h2 num = E * (E + (_Float16)2.0f);     // pk_add + pk_mul
    h2 den = num + (_Float16)2.0f;         // pk_add
    h2 r;
    r.x = rcph(den.x); r.y = rcph(den.y);  // 2x v_rcp_f16
    return x * num * r;                    // 2x pk_mul
}

// ---- pre-pass: z f32 -> fp16 (RNE), fully coalesced, BW-bound ----
__global__ __launch_bounds__(256)
void zcvt_kernel(const float* __restrict__ z, _Float16* __restrict__ zh) {
    const size_t i = (size_t)blockIdx.x * 256 + threadIdx.x;   // chunk id
    const float4 f0 = *reinterpret_cast<const float4*>(z + i * 8);
    const float4 f1 = *reinterpret_cast<const float4*>(z + i * 8 + 4);
    union { half8 h; uint4 u; } o;
    o.h[0] = (_Float16)f0.x; o.h[1] = (_Float16)f0.y;
    o.h[2] = (_Float16)f0.z; o.h[3] = (_Float16)f0.w;
    o.h[4] = (_Float16)f1.x; o.h[5] = (_Float16)f1.y;
    o.h[6] = (_Float16)f1.z; o.h[7] = (_Float16)f1.w;
    *reinterpret_cast<uint4*>(zh + i * 8) = o.u;
}

template <bool USE_H>
__global__ __launch_bounds__(512, 4)
void edge_decoder_kernel(const float*    __restrict__ z,
                         const _Float16* __restrict__ zh,
                         const int*      __restrict__ edge,
                         const float*    __restrict__ W1,
                         const float*    __restrict__ b1,
                         const float*    __restrict__ W2,
                         const float*    __restrict__ b2,
                         float*          __restrict__ out) {
    using frag_t = std::conditional_t<USE_H, half8, bf16x8>;

    __shared__ ushort xbuf[2][M_TILE * LDS_STRIDE];   // 2 x 8.7 KB
    __shared__ float  lpart[2][8][M_TILE];            // 2 KB

    const int t    = threadIdx.x;
    const int wave = t >> 6;          // 0..7
    const int lane = t & 63;
    const int quad = lane >> 4;
    const int nlo  = lane & 15;

    // ---- W1 -> fragments (wave owns hidden cols [32w, 32w+32)) ----
    // A-operand of the swapped mfma: lane l&15 = W1 row (hidden).
    frag_t bfrag[4][2];               // [ks][nt] = 32 VGPRs
    #pragma unroll
    for (int nt = 0; nt < 2; ++nt) {
        const int n = wave * 32 + nt * 16 + nlo;
        const float* wrow = W1 + n * D_IN;
        #pragma unroll
        for (int ks = 0; ks < 4; ++ks) {
            float4 w0 = *reinterpret_cast<const float4*>(wrow + ks * 32 + quad * 8);
            float4 w1 = *reinterpret_cast<const float4*>(wrow + ks * 32 + quad * 8 + 4);
            float wa[8] = {w0.x, w0.y, w0.z, w0.w, w1.x, w1.y, w1.z, w1.w};
            if constexpr (USE_H) {
                half8 hv;
                #pragma unroll
                for (int j = 0; j < 8; ++j) hv[j] = (_Float16)wa[j];
                bfrag[ks][nt] = hv;
            } else {
                bf16x8 bv;
                #pragma unroll
                for (int j = 0; j < 8; ++j) bv[j] = (__bf16)wa[j];
                bfrag[ks][nt] = bv;
            }
        }
    }
    // Swapped-D layout: lane holds hidden rows {nt*16 + quad*4 + r}, edge col nlo.
    // b1/w2 for this lane's 8 hidden rows, packed h2.
    h2 b1h[2][2], w2h[2][2];          // [nt][pair]
    #pragma unroll
    for (int nt = 0; nt < 2; ++nt) {
        const int nb = wave * 32 + nt * 16 + quad * 4;
        b1h[nt][0] = (h2){(_Float16)b1[nb],     (_Float16)b1[nb + 1]};
        b1h[nt][1] = (h2){(_Float16)b1[nb + 2], (_Float16)b1[nb + 3]};
        w2h[nt][0] = (h2){(_Float16)W2[nb],     (_Float16)W2[nb + 1]};
        w2h[nt][1] = (h2){(_Float16)W2[nb + 2], (_Float16)W2[nb + 3]};
    }
    const float b2f = b2[0];

    // ---- gather assignment: slot = edge within tile, cch = 8-elem chunk ----
    const int s_slot = t >> 4;        // 0..31
    const int cch    = t & 15;        // 0..15

    // ---- pipeline prologue ----
    int tile = blockIdx.x;
    float4 a0, a1, c0, c1;            // f32 path gather regs
    half8  ha, hc;                    // fp16 path gather regs
    {
        const int e = tile * M_TILE + s_slot;
        const int u = edge[e], v = edge[N_EDGES + e];
        if constexpr (USE_H) {
            ha = *reinterpret_cast<const half8*>(zh + (size_t)u * D_IN + cch * 8);
            hc = *reinterpret_cast<const half8*>(zh + (size_t)v * D_IN + cch * 8);
        } else {
            const float* zu = z + (size_t)u * D_IN + cch * 8;
            const float* zv = z + (size_t)v * D_IN + cch * 8;
            a0 = *reinterpret_cast<const float4*>(zu);
            a1 = *reinterpret_cast<const float4*>(zu + 4);
            c0 = *reinterpret_cast<const float4*>(zv);
            c1 = *reinterpret_cast<const float4*>(zv + 4);
        }
    }
    // next tile's gather addresses: USE_H stores precomputed BYTE offsets.
    int u_n, v_n;
    {
        const int t1 = min(tile + GRID, NTILES - 1);
        const int e1 = t1 * M_TILE + s_slot;
        if constexpr (USE_H) {
            u_n = edge[e1] * 256 + cch * 16;
            v_n = edge[N_EDGES + e1] * 256 + cch * 16;
        } else {
            u_n = edge[e1]; v_n = edge[N_EDGES + e1];
        }
    }

    int  p = 0;
    bool have_prev = false;
    int  prev_base = 0;

    for (; tile < NTILES; tile += GRID) {
        // ---- A: current tile's gathered pair-product -> xbuf[p] ----
        if constexpr (USE_H) {
            union { half8 h; uint4 u; } pr;
            pr.h = ha * hc;                       // 4x v_pk_mul_f16
            *reinterpret_cast<uint4*>(&xbuf[p][s_slot * LDS_STRIDE + cch * 8]) = pr.u;
        } else {
            F4H A0{a0}, A1{a1}, C0{c0}, C1{c1};
            unsigned int r0 = pkbf(A0.h[0] * C0.h[0]);
            unsigned int r1 = pkbf(A0.h[1] * C0.h[1]);
            unsigned int r2 = pkbf(A1.h[0] * C1.h[0]);
            unsigned int r3 = pkbf(A1.h[1] * C1.h[1]);
            *reinterpret_cast<uint4*>(&xbuf[p][s_slot * LDS_STRIDE + cch * 8]) =
                make_uint4(r0, r1, r2, r3);
        }

        // ---- C (pre-barrier): issue next tile's z loads + edge idx t+2 ----
        // (independent of the barrier; gets barrier-convergence + E + D slack)
        if constexpr (USE_H) {
            ha = *reinterpret_cast<const half8*>(
                     reinterpret_cast<const char*>(zh) + u_n);
            hc = *reinterpret_cast<const half8*>(
                     reinterpret_cast<const char*>(zh) + v_n);
        } else {
            const float* zu = z + (size_t)u_n * D_IN + cch * 8;
            const float* zv = z + (size_t)v_n * D_IN + cch * 8;
            a0 = *reinterpret_cast<const float4*>(zu);
            a1 = *reinterpret_cast<const float4*>(zu + 4);
            c0 = *reinterpret_cast<const float4*>(zv);
            c1 = *reinterpret_cast<const float4*>(zv + 4);
        }
        {
            const int t2 = min(tile + 2 * GRID, NTILES - 1);
            const int e2 = t2 * M_TILE + s_slot;
            if constexpr (USE_H) {
                u_n = edge[e2] * 256 + cch * 16;
                v_n = edge[N_EDGES + e2] * 256 + cch * 16;
            } else {
                u_n = edge[e2]; v_n = edge[N_EDGES + e2];
            }
        }

        // ---- B: the single barrier ----
        __syncthreads();

        // ---- E: combine + store PREVIOUS tile (lpart[p^1] sealed by barrier) ----
        if (have_prev) {
            if (t < M_TILE) {
                const int pp = p ^ 1;
                float logit = b2f;
                #pragma unroll
                for (int w = 0; w < 8; ++w) logit += lpart[pp][w][t];
                out[prev_base + t] = __builtin_amdgcn_rcpf(1.0f + __expf(-logit));
            }
        }

        // ---- D: swapped MFMA + packed-f16 epilogue -> lpart[p] ----
        f32x4 acc[2][2];   // [mt][nt]; D row = hidden (quad*4+r), col = edge (nlo)
        #pragma unroll
        for (int mt = 0; mt < 2; ++mt)
            #pragma unroll
            for (int nt = 0; nt < 2; ++nt)
                acc[mt][nt] = (f32x4){0.f, 0.f, 0.f, 0.f};

        #pragma unroll
        for (int ks = 0; ks < 4; ++ks) {
            frag_t af[2];   // x-fragment: lane l&15 = edge row mt*16+nlo
            #pragma unroll
            for (int mt = 0; mt < 2; ++mt)
                af[mt] = *reinterpret_cast<const frag_t*>(
                    &xbuf[p][(mt * 16 + nlo) * LDS_STRIDE + ks * 32 + quad * 8]);
            #pragma unroll
            for (int mt = 0; mt < 2; ++mt)
                #pragma unroll
                for (int nt = 0; nt < 2; ++nt) {
                    if constexpr (USE_H)
                        acc[mt][nt] = __builtin_amdgcn_mfma_f32_16x16x32_f16(
                            bfrag[ks][nt], af[mt], acc[mt][nt], 0, 0, 0);
                    else
                        acc[mt][nt] = __builtin_amdgcn_mfma_f32_16x16x32_bf16(
                            bfrag[ks][nt], af[mt], acc[mt][nt], 0, 0, 0);
                }
        }

        // Packed-f16 epilogue: cvt_pkrtz from acc, pk mish + fc2 dot, then
        // 2-step cross-quad reduce (xor16, xor32). Edge = mt*16 + nlo.
        #pragma unroll
        for (int mt = 0; mt < 2; ++mt) {
            h2 dot = (h2){(_Float16)0.0f, (_Float16)0.0f};
            #pragma unroll
            for (int nt = 0; nt < 2; ++nt) {
                h2 x0 = pkh(acc[mt][nt][0], acc[mt][nt][1]) + b1h[nt][0];
                h2 x1 = pkh(acc[mt][nt][2], acc[mt][nt][3]) + b1h[nt][1];
                dot += mish_h2(x0) * w2h[nt][0];
                dot += mish_h2(x1) * w2h[nt][1];
            }
            float s = (float)dot.x + (float)dot.y;
            s += __shfl_xor(s, 16);
            s += __shfl_xor(s, 32);
            if (quad == 0) lpart[p][wave][mt * 16 + nlo] = s;
        }

        have_prev = true;
        prev_base = tile * M_TILE;
        p ^= 1;
    }

    // ---- drain: last tile's logits ----
    __syncthreads();
    if (have_prev && t < M_TILE) {
        const int pp = p ^ 1;
        float logit = b2f;
        #pragma unroll
        for (int w = 0; w < 8; ++w) logit += lpart[pp][w][t];
        out[prev_base + t] = __builtin_amdgcn_rcpf(1.0f + __expf(-logit));
    }
}

extern "C" void kernel_launch(void* const* d_in, const int* in_sizes, int n_in,
                              void* d_out, int out_size, void* d_ws, size_t ws_size,
                              hipStream_t stream) {
    const float* z    = (const float*)d_in[0];
    const int*   edge = (const int*)d_in[1];
    const float* W1   = (const float*)d_in[2];
    const float* b1   = (const float*)d_in[3];
    const float* W2   = (const float*)d_in[4];
    const float* b2   = (const float*)d_in[5];
    float* out = (float*)d_out;

    const size_t zh_bytes = (size_t)N_NODES * D_IN * sizeof(_Float16);  // 25.6 MB
    if (d_ws != nullptr && ws_size >= zh_bytes) {
        _Float16* zh = (_Float16*)d_ws;
        zcvt_kernel<<<dim3(N_NODES * D_IN / 8 / 256), dim3(256), 0, stream>>>(z, zh);
        edge_decoder_kernel<true><<<dim3(GRID), dim3(512), 0, stream>>>(
            z, zh, edge, W1, b1, W2, b2, out);
    } else {
        edge_decoder_kernel<false><<<dim3(GRID), dim3(512), 0, stream>>>(
            z, nullptr, edge, W1, b1, W2, b2, out);
    }
}